// Round 3
// baseline (266.552 us; speedup 1.0000x reference)
//
#include <hip/hip_runtime.h>

#define NB   8192
#define HW   4096   // 64*64

// One 64-lane wave per sample; 4 waves (256 thr) per block; grid = NB/4.
// Each lane: 16 float4 loads (64 elems), accumulates
//   s0 = sum x, sj = sum j*x, sk = sum k*x, sq = sum (j^2+k^2)*x
// and per-lane argmax (strict '>', increasing scan order => first max).
// Wave shuffle reduce; lane 0 computes the closed-form per-sample loss
//   loss = (mx^2+my^2)*s0 - 2*mx*sj - 2*my*sk + sq
// and atomicAdds it straight into out[0] (zeroed by a memset node).
// No LDS, no __syncthreads, no second kernel.
__global__ __launch_bounds__(256) void per_sample_loss(const float* __restrict__ x,
                                                       float* __restrict__ out) {
    const int t    = threadIdx.x;
    const int lane = t & 63;
    const int wave = t >> 6;
    const int b    = blockIdx.x * 4 + wave;

    const float4* xp = (const float4*)(x + (size_t)b * HW);

    // Element index: e = 256*it + 4*lane + c.  k = e&63 const per (lane,c);
    // j = e>>6 = 4*it + j0_c.
    float kf[4], kk[4], jf[4];
    int   curIdx[4];
#pragma unroll
    for (int c = 0; c < 4; ++c) {
        const int e0 = 4 * lane + c;       // 0..255
        kf[c] = (float)(e0 & 63);
        kk[c] = kf[c] * kf[c];
        jf[c] = (float)(e0 >> 6);          // 0..3
        curIdx[c] = e0;
    }

    float s0 = 0.f, sj = 0.f, sk = 0.f, sq = 0.f;
    float maxv = -__builtin_inff();
    int   maxi = 0;

#pragma unroll
    for (int it = 0; it < 16; ++it) {
        const float4 v4 = xp[it * 64 + lane];
        const float vv[4] = {v4.x, v4.y, v4.z, v4.w};
#pragma unroll
        for (int c = 0; c < 4; ++c) {
            const float v = vv[c];
            const float q = fmaf(jf[c], jf[c], kk[c]);   // j^2 + k^2
            s0 += v;
            sj = fmaf(jf[c], v, sj);
            sk = fmaf(kf[c], v, sk);
            sq = fmaf(q, v, sq);
            const bool gt = v > maxv;
            maxv = gt ? v : maxv;
            maxi = gt ? curIdx[c] : maxi;
        }
#pragma unroll
        for (int c = 0; c < 4; ++c) { jf[c] += 4.0f; curIdx[c] += 256; }
    }

    // Wave reduce (64 lanes); ties -> smaller flat index (first max).
#pragma unroll
    for (int off = 32; off > 0; off >>= 1) {
        s0 += __shfl_down(s0, off);
        sj += __shfl_down(sj, off);
        sk += __shfl_down(sk, off);
        sq += __shfl_down(sq, off);
        const float ov = __shfl_down(maxv, off);
        const int   oi = __shfl_down(maxi, off);
        const bool take = (ov > maxv) || (ov == maxv && oi < maxi);
        maxv = take ? ov : maxv;
        maxi = take ? oi : maxi;
    }

    if (lane == 0) {
        const float mx = (float)(maxi >> 6);
        const float my = (float)(maxi & 63);
        const float loss =
            (mx * mx + my * my) * s0 - 2.f * mx * sj - 2.f * my * sk + sq;
        atomicAdd(out, loss);   // device-scope HW fp32 atomic on gfx950
    }
}

extern "C" void kernel_launch(void* const* d_in, const int* in_sizes, int n_in,
                              void* d_out, int out_size, void* d_ws, size_t ws_size,
                              hipStream_t stream) {
    const float* x = (const float*)d_in[0];
    float* out = (float*)d_out;

    // d_out is poisoned to 0xAA before every timed call; zero it with a
    // capture-legal stream memset node, then accumulate atomically.
    hipMemsetAsync(out, 0, sizeof(float), stream);
    per_sample_loss<<<NB / 4, 256, 0, stream>>>(x, out);
}

// Round 4
// 188.371 us; speedup vs baseline: 1.4150x; 1.4150x over previous
//
#include <hip/hip_runtime.h>

#define NB   8192
#define HW   4096   // 64*64

// One 64-lane wave per sample; 4 waves (256 thr) per block; grid = NB/4.
// All 16 float4 loads are staged into registers up-front (deep MLP — the
// R2 version let the compiler serialize to ~4 outstanding loads, VGPR=28),
// then the closed-form sums are computed from registers:
//   loss = (mx^2+my^2)*s0 - 2*mx*sj - 2*my*sk + sq
// with s0=sum x, sj=sum j*x, sk=sum k*x, sq=sum (j^2+k^2)*x and (mx,my) the
// first (row-major) argmax. Wave shuffle reduce; partials to ws; second tiny
// kernel reduces 8192 partials. No atomics, no LDS in the main kernel.
__global__ __launch_bounds__(256) void per_sample_loss(const float* __restrict__ x,
                                                       float* __restrict__ ws) {
    const int t    = threadIdx.x;
    const int lane = t & 63;
    const int wave = t >> 6;
    const int b    = blockIdx.x * 4 + wave;

    const float4* xp = (const float4*)(x + (size_t)b * HW) + lane;

    // Stage the whole sample: 16 independent 16B loads, no dependent VALU
    // in between -> compiler can keep all 16 in flight.
    float4 r[16];
#pragma unroll
    for (int it = 0; it < 16; ++it) r[it] = xp[it * 64];

    // e = it*256 + 4*lane + c :
    //   j = e>>6 = 4*it + (lane>>4)          (same for all 4 components)
    //   k = e&63 = 4*(lane&15) + c           (independent of it)
    float kf[4], kk[4];
#pragma unroll
    for (int c = 0; c < 4; ++c) {
        kf[c] = (float)(4 * (lane & 15) + c);
        kk[c] = kf[c] * kf[c];
    }

    float jf = (float)(lane >> 4);
    int   eb = 4 * lane;              // flat index of component 0 at iter 0

    float s0 = 0.f, sj = 0.f, sk = 0.f, sq = 0.f;
    float maxv = -__builtin_inff();
    int   maxi = 0;

#pragma unroll
    for (int it = 0; it < 16; ++it) {
        const float vv[4] = {r[it].x, r[it].y, r[it].z, r[it].w};
#pragma unroll
        for (int c = 0; c < 4; ++c) {
            const float v = vv[c];
            s0 += v;
            sj = fmaf(jf, v, sj);
            sk = fmaf(kf[c], v, sk);
            sq = fmaf(fmaf(jf, jf, kk[c]), v, sq);
            // strict '>' with increasing per-lane scan order => first max
            const bool gt = v > maxv;
            maxv = gt ? v : maxv;
            maxi = gt ? eb + c : maxi;
        }
        jf += 4.0f;
        eb += 256;
    }

    // Wave reduce (64 lanes); ties -> smaller flat index (first max).
#pragma unroll
    for (int off = 32; off > 0; off >>= 1) {
        s0 += __shfl_down(s0, off);
        sj += __shfl_down(sj, off);
        sk += __shfl_down(sk, off);
        sq += __shfl_down(sq, off);
        const float ov = __shfl_down(maxv, off);
        const int   oi = __shfl_down(maxi, off);
        const bool take = (ov > maxv) || (ov == maxv && oi < maxi);
        maxv = take ? ov : maxv;
        maxi = take ? oi : maxi;
    }

    if (lane == 0) {
        const float mx = (float)(maxi >> 6);
        const float my = (float)(maxi & 63);
        ws[b] = (mx * mx + my * my) * s0 - 2.f * mx * sj - 2.f * my * sk + sq;
    }
}

__global__ __launch_bounds__(256) void final_reduce(const float* __restrict__ ws,
                                                    float* __restrict__ out) {
    const int t = threadIdx.x;
    float s = 0.f;
#pragma unroll
    for (int i = 0; i < NB / 256; ++i) s += ws[i * 256 + t];
#pragma unroll
    for (int off = 32; off > 0; off >>= 1) s += __shfl_down(s, off);
    __shared__ float l[4];
    if ((t & 63) == 0) l[t >> 6] = s;
    __syncthreads();
    if (t == 0) out[0] = l[0] + l[1] + l[2] + l[3];
}

extern "C" void kernel_launch(void* const* d_in, const int* in_sizes, int n_in,
                              void* d_out, int out_size, void* d_ws, size_t ws_size,
                              hipStream_t stream) {
    const float* x = (const float*)d_in[0];
    float* out = (float*)d_out;
    float* ws  = (float*)d_ws;   // 8192 floats = 32 KiB scratch

    per_sample_loss<<<NB / 4, 256, 0, stream>>>(x, ws);
    final_reduce<<<1, 256, 0, stream>>>(ws, out);
}

// Round 6
// 177.095 us; speedup vs baseline: 1.5051x; 1.0637x over previous
//
#include <hip/hip_runtime.h>

#define NB   8192
#define HW   4096   // 64*64

typedef float vfloat4 __attribute__((ext_vector_type(4)));  // native vector for nt-load

// One 64-lane wave per sample; 4 waves (256 thr) per block; grid = NB/4.
// Loads are NONTEMPORAL (streamed once, zero reuse -> bypass cache
// allocation) with a depth-4 register ring prefetch. Accumulates
//   s0 = sum x, sj = sum j*x, sk = sum k*x, sq = sum (j^2+k^2)*x
// plus first-max argmax (strict '>', increasing per-lane scan order).
// Wave shuffle reduce; lane 0 writes the closed-form per-sample loss
//   loss = (mx^2+my^2)*s0 - 2*mx*sj - 2*my*sk + sq
// to ws[b]. Tiny second kernel reduces the 8192 partials.
__global__ __launch_bounds__(256) void per_sample_loss(const float* __restrict__ x,
                                                       float* __restrict__ ws) {
    const int t    = threadIdx.x;
    const int lane = t & 63;
    const int wave = t >> 6;
    const int b    = blockIdx.x * 4 + wave;

    const vfloat4* xp = (const vfloat4*)(x + (size_t)b * HW) + lane;

    // Depth-4 nontemporal prefetch ring.
    vfloat4 r[4];
#pragma unroll
    for (int p = 0; p < 4; ++p) r[p] = __builtin_nontemporal_load(xp + p * 64);

    // e = it*256 + 4*lane + c :
    //   j = e>>6 = 4*it + (lane>>4)   (same for all 4 components of a float4)
    //   k = e&63 = 4*(lane&15) + c    (independent of it)
    float kf[4], kk[4];
#pragma unroll
    for (int c = 0; c < 4; ++c) {
        kf[c] = (float)(4 * (lane & 15) + c);
        kk[c] = kf[c] * kf[c];
    }

    float jf = (float)(lane >> 4);
    int   eb = 4 * lane;              // flat index of component 0 at iter 0

    float s0 = 0.f, sj = 0.f, sk = 0.f, sq = 0.f;
    float maxv = -__builtin_inff();
    int   maxi = 0;

#pragma unroll
    for (int it = 0; it < 16; ++it) {
        const vfloat4 v4 = r[it & 3];
        if (it + 4 < 16)
            r[it & 3] = __builtin_nontemporal_load(xp + (it + 4) * 64);
#pragma unroll
        for (int c = 0; c < 4; ++c) {
            const float v = v4[c];
            s0 += v;
            sj = fmaf(jf, v, sj);
            sk = fmaf(kf[c], v, sk);
            sq = fmaf(fmaf(jf, jf, kk[c]), v, sq);
            const bool gt = v > maxv;   // strict '>' => first max per lane
            maxv = gt ? v : maxv;
            maxi = gt ? eb + c : maxi;
        }
        jf += 4.0f;
        eb += 256;
    }

    // Wave reduce (64 lanes); ties -> smaller flat index (first max).
#pragma unroll
    for (int off = 32; off > 0; off >>= 1) {
        s0 += __shfl_down(s0, off);
        sj += __shfl_down(sj, off);
        sk += __shfl_down(sk, off);
        sq += __shfl_down(sq, off);
        const float ov = __shfl_down(maxv, off);
        const int   oi = __shfl_down(maxi, off);
        const bool take = (ov > maxv) || (ov == maxv && oi < maxi);
        maxv = take ? ov : maxv;
        maxi = take ? oi : maxi;
    }

    if (lane == 0) {
        const float mx = (float)(maxi >> 6);
        const float my = (float)(maxi & 63);
        ws[b] = (mx * mx + my * my) * s0 - 2.f * mx * sj - 2.f * my * sk + sq;
    }
}

__global__ __launch_bounds__(256) void final_reduce(const float* __restrict__ ws,
                                                    float* __restrict__ out) {
    const int t = threadIdx.x;
    float s = 0.f;
#pragma unroll
    for (int i = 0; i < NB / 256; ++i) s += ws[i * 256 + t];
#pragma unroll
    for (int off = 32; off > 0; off >>= 1) s += __shfl_down(s, off);
    __shared__ float l[4];
    if ((t & 63) == 0) l[t >> 6] = s;
    __syncthreads();
    if (t == 0) out[0] = l[0] + l[1] + l[2] + l[3];
}

extern "C" void kernel_launch(void* const* d_in, const int* in_sizes, int n_in,
                              void* d_out, int out_size, void* d_ws, size_t ws_size,
                              hipStream_t stream) {
    const float* x = (const float*)d_in[0];
    float* out = (float*)d_out;
    float* ws  = (float*)d_ws;   // 8192 floats = 32 KiB scratch

    per_sample_loss<<<NB / 4, 256, 0, stream>>>(x, ws);
    final_reduce<<<1, 256, 0, stream>>>(ws, out);
}